// Round 2
// baseline (487.656 us; speedup 1.0000x reference)
//
#include <hip/hip_runtime.h>
#include <math.h>

// Strategy: counting-sort edges into 4096 output tiles (64 rows x 256 cols =
// 64 KB fp32 each), then one block per tile builds the tile in LDS (zero +
// LDS atomicMax on int bits -- exact for non-negative floats) and streams it
// out with coalesced int4 stores. Every output line is written exactly once
// (zeros included): no global memset, no global atomics on the output.

#define TB 256       // threads per block
#define NPART 256    // partition blocks for hist/reorder
#define BINS 4096    // (8192/64) * (8192/256)
#define COLT 32      // column tiles per row of tiles

// ---------------- fast path ----------------

__global__ __launch_bounds__(256) void hist_kernel(
    const int* __restrict__ rows, const int* __restrict__ cols,
    int* __restrict__ hist, int E, int chunk) {
  __shared__ int lh[BINS];
  for (int i = threadIdx.x; i < BINS; i += TB) lh[i] = 0;
  __syncthreads();
  int b = blockIdx.x;
  int s = b * chunk;
  int e = min(s + chunk, E);
  for (int i = s + threadIdx.x; i < e; i += TB) {
    int bin = (rows[i] >> 6) * COLT + (cols[i] >> 8);
    atomicAdd(&lh[bin], 1);
  }
  __syncthreads();
  // staggered start so concurrent blocks hit different hist lines
  int start = (b * 521) & (BINS - 1);
  for (int i = threadIdx.x; i < BINS; i += TB) {
    int bin = (start + i) & (BINS - 1);
    int c = lh[bin];
    if (c) atomicAdd(&hist[bin], c);
  }
}

__global__ __launch_bounds__(256) void scan_kernel(
    const int* __restrict__ hist, int* __restrict__ bin_base,
    int* __restrict__ cursors) {
  // single block, 256 threads, scans BINS=4096 counts (16 per thread)
  __shared__ int partial[TB];
  const int per = BINS / TB;  // 16
  int t = threadIdx.x;
  int local[per];
  int sum = 0;
  for (int i = 0; i < per; ++i) {
    local[i] = hist[t * per + i];
    sum += local[i];
  }
  partial[t] = sum;
  __syncthreads();
  // Hillis-Steele inclusive scan over 256 partials
  for (int off = 1; off < TB; off <<= 1) {
    int v = (t >= off) ? partial[t - off] : 0;
    __syncthreads();
    partial[t] += v;
    __syncthreads();
  }
  int run = (t == 0) ? 0 : partial[t - 1];
  for (int i = 0; i < per; ++i) {
    int bin = t * per + i;
    bin_base[bin] = run;
    cursors[bin * 16] = run;  // padded cursors: one per 64B line
    run += local[i];
  }
  if (t == TB - 1) bin_base[BINS] = run;
}

__global__ __launch_bounds__(256) void reorder_kernel(
    const float* __restrict__ w, const int* __restrict__ rows,
    const int* __restrict__ cols, int* __restrict__ cursors,
    uint2* __restrict__ sorted, int E, int chunk) {
  __shared__ int lds[BINS];
  for (int i = threadIdx.x; i < BINS; i += TB) lds[i] = 0;
  __syncthreads();
  int b = blockIdx.x;
  int s = b * chunk;
  int e = min(s + chunk, E);
  // pass 1: per-block histogram
  for (int i = s + threadIdx.x; i < e; i += TB) {
    int bin = (rows[i] >> 6) * COLT + (cols[i] >> 8);
    atomicAdd(&lds[bin], 1);
  }
  __syncthreads();
  // reserve contiguous ranges per nonzero bin (staggered to spread lines)
  int start = (b * 521) & (BINS - 1);
  for (int i = threadIdx.x; i < BINS; i += TB) {
    int bin = (start + i) & (BINS - 1);
    int c = lds[bin];
    int base = 0;
    if (c) base = atomicAdd(&cursors[bin * 16], c);
    lds[bin] = base;  // each bin owned by exactly one thread here
  }
  __syncthreads();
  // pass 2: place edges
  for (int i = s + threadIdx.x; i < e; i += TB) {
    int r = rows[i], c = cols[i];
    int bin = (r >> 6) * COLT + (c >> 8);
    int pos = atomicAdd(&lds[bin], 1);
    int loc = ((r & 63) << 8) | (c & 255);
    sorted[pos] = make_uint2((unsigned)__float_as_int(w[i]), (unsigned)loc);
  }
}

__global__ __launch_bounds__(256) void paint_kernel(
    const uint2* __restrict__ sorted, const int* __restrict__ bin_base,
    float* __restrict__ out, int n) {
  __shared__ int tile[64 * 256];  // 64 KB -> 2 blocks/CU
  int bin = blockIdx.x;
  for (int i = threadIdx.x; i < 64 * 256; i += TB) tile[i] = 0;
  __syncthreads();
  int s = bin_base[bin], e = bin_base[bin + 1];
  for (int i = s + threadIdx.x; i < e; i += TB) {
    uint2 rec = sorted[i];
    atomicMax(&tile[rec.y], (int)rec.x);  // exact: weights >= 0
  }
  __syncthreads();
  int row0 = (bin >> 5) << 6;   // (bin / COLT) * 64
  int col0 = (bin & 31) << 8;   // (bin % COLT) * 256
  const int4* t4 = (const int4*)tile;
  // 4096 int4 per tile; 64 int4 per row -> one wave instruction = one row (1 KB)
  for (int v = threadIdx.x; v < 4096; v += TB) {
    int r = v >> 6;
    int cq = (v & 63) << 2;
    *(int4*)&out[(size_t)(row0 + r) * n + (size_t)(col0 + cq)] = t4[v];
  }
}

// ---------------- fallback path (round-1 kernels) ----------------

__global__ void scatter_max_vec4(const float4* __restrict__ w4,
                                 const int4* __restrict__ r4,
                                 const int4* __restrict__ c4,
                                 int* __restrict__ out_bits,
                                 int num_vec, int n) {
  int i = blockIdx.x * blockDim.x + threadIdx.x;
  int stride = gridDim.x * blockDim.x;
  for (; i < num_vec; i += stride) {
    float4 w = w4[i];
    int4 r = r4[i];
    int4 c = c4[i];
    atomicMax(&out_bits[(long long)r.x * n + c.x], __float_as_int(w.x));
    atomicMax(&out_bits[(long long)r.y * n + c.y], __float_as_int(w.y));
    atomicMax(&out_bits[(long long)r.z * n + c.z], __float_as_int(w.z));
    atomicMax(&out_bits[(long long)r.w * n + c.w], __float_as_int(w.w));
  }
}

__global__ void scatter_max_tail(const float* __restrict__ w,
                                 const int* __restrict__ rows,
                                 const int* __restrict__ cols,
                                 int* __restrict__ out_bits,
                                 int start, int E, int n) {
  int i = start + blockIdx.x * blockDim.x + threadIdx.x;
  if (i < E) {
    atomicMax(&out_bits[(long long)rows[i] * n + cols[i]],
              __float_as_int(w[i]));
  }
}

extern "C" void kernel_launch(void* const* d_in, const int* in_sizes, int n_in,
                              void* d_out, int out_size, void* d_ws, size_t ws_size,
                              hipStream_t stream) {
  const float* weights = (const float*)d_in[0];
  const int* rows = (const int*)d_in[1];
  const int* cols = (const int*)d_in[2];
  const int E = in_sizes[0];
  int n = (int)(sqrt((double)out_size) + 0.5);

  // workspace layout
  const size_t off_base = 0;                       // bin_base: (BINS+1) ints
  const size_t off_cur = 32 * 1024;                // cursors: BINS*16 ints (256 KB)
  const size_t off_hist = off_cur + 256 * 1024;    // hist: BINS ints (16 KB)
  const size_t off_sorted = off_hist + 32 * 1024;  // sorted: E * 8 B
  const size_t need = off_sorted + (size_t)E * 8;

  if (n == 8192 && E > 0 && ws_size >= need) {
    char* ws = (char*)d_ws;
    int* bin_base = (int*)(ws + off_base);
    int* cursors = (int*)(ws + off_cur);
    int* hist = (int*)(ws + off_hist);
    uint2* sorted = (uint2*)(ws + off_sorted);

    int chunk = (E + NPART - 1) / NPART;
    hipMemsetAsync(hist, 0, BINS * sizeof(int), stream);
    hist_kernel<<<NPART, TB, 0, stream>>>(rows, cols, hist, E, chunk);
    scan_kernel<<<1, TB, 0, stream>>>(hist, bin_base, cursors);
    reorder_kernel<<<NPART, TB, 0, stream>>>(weights, rows, cols, cursors,
                                             sorted, E, chunk);
    paint_kernel<<<BINS, TB, 0, stream>>>(sorted, bin_base, (float*)d_out, n);
  } else {
    // fallback: memset + global atomic scatter
    int* out_bits = (int*)d_out;
    hipMemsetAsync(d_out, 0, (size_t)out_size * sizeof(float), stream);
    int num_vec = E / 4;
    int tail_start = num_vec * 4;
    if (num_vec > 0) {
      int grid = (num_vec + 255) / 256;
      if (grid > 2048) grid = 2048;
      scatter_max_vec4<<<grid, 256, 0, stream>>>(
          (const float4*)weights, (const int4*)rows, (const int4*)cols,
          out_bits, num_vec, n);
    }
    if (tail_start < E) {
      int grid = (E - tail_start + 255) / 256;
      scatter_max_tail<<<grid, 256, 0, stream>>>(weights, rows, cols, out_bits,
                                                 tail_start, E, n);
    }
  }
}